// Round 10
// baseline (106.696 us; speedup 1.0000x reference)
//
#include <hip/hip_runtime.h>
#include <hip/hip_fp16.h>

#define HH 128
#define WW 128
#define CC 64
#define OO 64
#define HWSZ (HH*WW)

typedef _Float16 f16x8 __attribute__((ext_vector_type(8)));
typedef float    f32x4 __attribute__((ext_vector_type(4)));

__device__ __forceinline__ unsigned short f2h(float f) {
    return __half_as_ushort(__float2half_rn(f));
}

// ---------------------------------------------------------------------------
// K0: prep_all. z<4: x NCHW fp32 -> NHWC fp16 (LDS-tiled transpose).
//     z==4: weight repack -> fp16 in MFMA B-fragment-major order:
//       wdtf[kc(18)][nt(4)][lane(64)][j(8)] : o=nt*16+(l&15), c=(kc&1)*32+((l>>4)&3)*8+j, k=kc>>1
//       wotf[kc(18)][nt(2)][lane(64)][j(8)] : same, oc>=18 zero-padded
// ---------------------------------------------------------------------------
__global__ __launch_bounds__(256) void prep_all(const float* __restrict__ x,
                                                const float* __restrict__ wd,
                                                const float* __restrict__ wo,
                                                unsigned short* __restrict__ xh,
                                                unsigned short* __restrict__ wdtf,
                                                unsigned short* __restrict__ wotf) {
    int t = threadIdx.x;
    if (blockIdx.z == 4) {
        int i = (blockIdx.y * 2 + blockIdx.x) * 256 + t;
        if (i < 36864) {
            int j = i & 7, l = (i >> 3) & 63, nt = (i >> 9) & 3, kcb = i >> 11;
            int k = kcb >> 1, cb = kcb & 1;
            int o = nt * 16 + (l & 15);
            int c = cb * 32 + ((l >> 4) & 3) * 8 + j;
            wdtf[i] = f2h(wd[(o * 64 + c) * 9 + k]);
        } else if (i < 36864 + 18432) {
            int jdx = i - 36864;
            int j = jdx & 7, l = (jdx >> 3) & 63, nt = (jdx >> 9) & 1, kcb = jdx >> 10;
            int k = kcb >> 1, cb = kcb & 1;
            int oc = nt * 16 + (l & 15);
            int c = cb * 32 + ((l >> 4) & 3) * 8 + j;
            wotf[jdx] = f2h(oc < 18 ? wo[(oc * 64 + c) * 9 + k] : 0.0f);
        }
        return;
    }
    __shared__ float tile[64 * 65];
    int w0 = blockIdx.x * 64, h = blockIdx.y, b = blockIdx.z;
    const float* xb = x + ((long)b * CC * HWSZ) + h * WW + w0;
#pragma unroll
    for (int i = 0; i < 16; ++i) {
        int idx = i * 256 + t; int c = idx >> 6, w = idx & 63;
        tile[c * 65 + w] = xb[c * HWSZ + w];
    }
    __syncthreads();
    unsigned short* xo = xh + ((long)((b * HH + h) * WW + w0)) * CC;
#pragma unroll
    for (int i = 0; i < 8; ++i) {
        int idx = i * 256 + t; int w = idx >> 5, c = (idx & 31) * 2;
        ushort2 u;
        u.x = f2h(tile[c * 65 + w]);
        u.y = f2h(tile[(c + 1) * 65 + w]);
        *(ushort2*)(xo + w * CC + c) = u;
    }
}

// ---------------------------------------------------------------------------
// K1: fused offset-conv + deform-conv. Block = (b,h,64px).
// Phase A: stage rows h-1..h+1 -> LDS (xr), 9x MFMA with frag-major wotf,
//   offsets -> LDS offs[64][20].
// Phase B: B panel (18 frags) in VGPRs; ONE 64-px tile: sample all 9 k
//   (4 threads/px x 16ch -> address math amortized 2x vs 32-px tiles,
//   packed-fp16 bilinear) -> val_s[64][584] -> barrier ->
//   18x(4 ds_read_b128 + 4 MFMA), no further barriers.
// xr and val_s share one LDS union (74.75 KB); + offs 5 KB = 79.9 KB
// -> exactly 2 blocks/CU.
// ---------------------------------------------------------------------------
__global__ __launch_bounds__(256, 2) void fused_dcn(const unsigned short* __restrict__ xh,
                                                    const unsigned short* __restrict__ wotf,
                                                    const float* __restrict__ b_off,
                                                    const unsigned short* __restrict__ wdtf,
                                                    const float* __restrict__ b_dcn,
                                                    float* __restrict__ out) {
    __shared__ __attribute__((aligned(16))) unsigned short shm[64 * 584]; // union
    __shared__ float offs[64 * 20];
    unsigned short* xr    = shm;   // phase A: [row(3)][px(66,pad68)][ch(64,pad72)]
    unsigned short* val_s = shm;   // phase B: [px(64)][K(576,pad584)]

    int w0 = blockIdx.x * 64, h = blockIdx.y, b = blockIdx.z;
    int t = threadIdx.x;
    int l = t & 63, wv = t >> 6;
    int m = l & 15, q = l >> 4;

    // ================= phase A: offset conv =================
#pragma unroll
    for (int i = 0; i < 7; ++i) {
        int idx = i * 256 + t;
        if (idx < 1584) {
            int r = idx / 528;
            int rem = idx - r * 528;
            int p = rem >> 3, cc = rem & 7;
            int y = h + r - 1, wx = w0 - 1 + p;
            uint4 v = make_uint4(0u, 0u, 0u, 0u);
            if (((unsigned)y < HH) && ((unsigned)wx < WW))
                v = *(const uint4*)(xh + ((long)((b * HH + y) * WW + wx)) * CC + cc * 8);
            *(uint4*)&xr[(r * 68 + p) * 72 + cc * 8] = v;
        }
    }
    __syncthreads();
    {
        int px0 = wv * 16;
        f32x4 acc0 = {0.f, 0.f, 0.f, 0.f}, acc1 = {0.f, 0.f, 0.f, 0.f};
#pragma unroll
        for (int k = 0; k < 9; ++k) {
            int ky = k / 3, kx = k - ky * 3;
            const unsigned short* ar = &xr[(ky * 68 + px0 + m + kx) * 72 + q * 8];
            f16x8 a0 = *(const f16x8*)(ar);
            f16x8 a1 = *(const f16x8*)(ar + 32);
            const unsigned short* bk = wotf + (k * 2) * 2 * 512 + l * 8;
            f16x8 b00 = *(const f16x8*)(bk);
            f16x8 b01 = *(const f16x8*)(bk + 512);
            f16x8 b10 = *(const f16x8*)(bk + 1024);
            f16x8 b11 = *(const f16x8*)(bk + 1536);
            acc0 = __builtin_amdgcn_mfma_f32_16x16x32_f16(a0, b00, acc0, 0, 0, 0);
            acc0 = __builtin_amdgcn_mfma_f32_16x16x32_f16(a1, b10, acc0, 0, 0, 0);
            acc1 = __builtin_amdgcn_mfma_f32_16x16x32_f16(a0, b01, acc1, 0, 0, 0);
            acc1 = __builtin_amdgcn_mfma_f32_16x16x32_f16(a1, b11, acc1, 0, 0, 0);
        }
        float bo0 = b_off[m];
#pragma unroll
        for (int r = 0; r < 4; ++r)
            offs[(px0 + q * 4 + r) * 20 + m] = acc0[r] + bo0;
        if (m < 2) {
            float bo1 = b_off[16 + m];
#pragma unroll
            for (int r = 0; r < 4; ++r)
                offs[(px0 + q * 4 + r) * 20 + 16 + m] = acc1[r] + bo1;
        }
    }
    __syncthreads();   // offs ready; xr dead; val_s may now overwrite shm

    // ================= phase B: deform conv =================
    int spx = t >> 2, ch16 = (t & 3) * 16;   // sampler: pixel 0..63, 32B chunk

    f16x8 Breg[18];
#pragma unroll
    for (int kc = 0; kc < 18; ++kc)
        Breg[kc] = *(const f16x8*)(wdtf + (kc * 4 + wv) * 512 + l * 8);

    const unsigned short* xb = xh + (long)b * HWSZ * CC;
    const float* oprow = &offs[spx * 20];

#pragma unroll
    for (int k = 0; k < 9; ++k) {
        int ky = k / 3, kx = k - ky * 3;
        float2 ov = *(const float2*)(oprow + 2 * k);
        float py  = (float)(h + ky - 1) + ov.x;
        float pxf = (float)(w0 + spx + kx - 1) + ov.y;
        float y0f = floorf(py), x0f = floorf(pxf);
        float wy = py - y0f, wx = pxf - x0f;
        int y0 = (int)y0f, x0 = (int)x0f, y1 = y0 + 1, x1 = x0 + 1;
        bool vy0 = (unsigned)y0 < HH, vy1 = (unsigned)y1 < HH;
        bool vx0 = (unsigned)x0 < WW, vx1 = (unsigned)x1 < WW;
        int y0c = min(max(y0, 0), HH - 1), y1c = min(max(y1, 0), HH - 1);
        int x0c = min(max(x0, 0), WW - 1), x1c = min(max(x1, 0), WW - 1);
        _Float16 h0 = (_Float16)((vy0 && vx0) ? (1.f - wy) * (1.f - wx) : 0.f);
        _Float16 h1 = (_Float16)((vy0 && vx1) ? (1.f - wy) * wx : 0.f);
        _Float16 h2 = (_Float16)((vy1 && vx0) ? wy * (1.f - wx) : 0.f);
        _Float16 h3 = (_Float16)((vy1 && vx1) ? wy * wx : 0.f);
        const unsigned short* p00 = xb + (y0c * WW + x0c) * CC + ch16;
        const unsigned short* p01 = xb + (y0c * WW + x1c) * CC + ch16;
        const unsigned short* p10 = xb + (y1c * WW + x0c) * CC + ch16;
        const unsigned short* p11 = xb + (y1c * WW + x1c) * CC + ch16;
        f16x8 s00a = *(const f16x8*)p00, s00b = *(const f16x8*)(p00 + 8);
        f16x8 s01a = *(const f16x8*)p01, s01b = *(const f16x8*)(p01 + 8);
        f16x8 s10a = *(const f16x8*)p10, s10b = *(const f16x8*)(p10 + 8);
        f16x8 s11a = *(const f16x8*)p11, s11b = *(const f16x8*)(p11 + 8);
        f16x8 alo = s00a * h0 + s01a * h1 + s10a * h2 + s11a * h3;  // v_pk_fma_f16
        f16x8 ahi = s00b * h0 + s01b * h1 + s10b * h2 + s11b * h3;
        *(f16x8*)&val_s[spx * 584 + k * 64 + ch16] = alo;
        *(f16x8*)&val_s[spx * 584 + k * 64 + ch16 + 8] = ahi;
    }
    __syncthreads();

    // ---- GEMM: K=576, B in regs, 4 px-tiles per wave, no barriers ----
    f32x4 acc[4];
#pragma unroll
    for (int i = 0; i < 4; ++i) acc[i] = f32x4{0.f, 0.f, 0.f, 0.f};
#pragma unroll
    for (int kc = 0; kc < 18; ++kc) {
#pragma unroll
        for (int p = 0; p < 4; ++p) {
            f16x8 a = *(const f16x8*)&val_s[(p * 16 + m) * 584 + kc * 32 + q * 8];
            acc[p] = __builtin_amdgcn_mfma_f32_16x16x32_f16(a, Breg[kc], acc[p], 0, 0, 0);
        }
    }

    // ---- epilogue: o = wv*16+m, px = p*16 + q*4 + r ----
    int o = wv * 16 + m;
    float bo = b_dcn[o];
    float* outo = out + ((long)(b * OO + o)) * HWSZ + h * WW + w0;
#pragma unroll
    for (int p = 0; p < 4; ++p) {
        f32x4 r = acc[p];
        r[0] += bo; r[1] += bo; r[2] += bo; r[3] += bo;
        *(f32x4*)(outo + p * 16 + q * 4) = r;
    }
}

// ---------------------------------------------------------------------------
extern "C" void kernel_launch(void* const* d_in, const int* in_sizes, int n_in,
                              void* d_out, int out_size, void* d_ws, size_t ws_size,
                              hipStream_t stream) {
    const float* x     = (const float*)d_in[0];
    const float* w_off = (const float*)d_in[1];
    const float* b_off = (const float*)d_in[2];
    const float* w_dcn = (const float*)d_in[3];
    const float* b_dcn = (const float*)d_in[4];
    float* out = (float*)d_out;

    char* ws = (char*)d_ws;
    unsigned short* xh   = (unsigned short*)ws;              //  8,388,608 B
    unsigned short* wdtf = (unsigned short*)(ws + 8388608);  //     73,728 B
    unsigned short* wotf = (unsigned short*)(ws + 8462336);  //     36,864 B

    hipLaunchKernelGGL(prep_all, dim3(2, 128, 5), dim3(256), 0, stream,
                       x, w_dcn, w_off, xh, wdtf, wotf);
    hipLaunchKernelGGL(fused_dcn, dim3(2, 128, 4), dim3(256), 0, stream,
                       xh, wotf, b_off, wdtf, b_dcn, out);
}

// Round 11
// 105.710 us; speedup vs baseline: 1.0093x; 1.0093x over previous
//
#include <hip/hip_runtime.h>
#include <hip/hip_fp16.h>

#define HH 128
#define WW 128
#define CC 64
#define OO 64
#define HWSZ (HH*WW)

typedef _Float16 f16x8  __attribute__((ext_vector_type(8)));
typedef float    f32x4  __attribute__((ext_vector_type(4)));
typedef float    f32x16 __attribute__((ext_vector_type(16)));

__device__ __forceinline__ unsigned short f2h(float f) {
    return __half_as_ushort(__float2half_rn(f));
}

// ---------------------------------------------------------------------------
// K0: prep_all. z<4: x NCHW fp32 -> NHWC fp16 (LDS-tiled transpose).
//     z==4: weight repack -> fp16 fragment-major:
//       wdtf[s(36)][ot(2)][lane(64)][j(8)] for 32x32x16 deform GEMM:
//         K = s*16 + (l>>5)*8 + j (K = k*64+c), o = ot*32 + (l&31)
//       wotf[kc(18)][nt(2)][lane(64)][j(8)] for 16x16x32 offset conv (as before)
// ---------------------------------------------------------------------------
__global__ __launch_bounds__(256) void prep_all(const float* __restrict__ x,
                                                const float* __restrict__ wd,
                                                const float* __restrict__ wo,
                                                unsigned short* __restrict__ xh,
                                                unsigned short* __restrict__ wdtf,
                                                unsigned short* __restrict__ wotf) {
    int t = threadIdx.x;
    if (blockIdx.z == 4) {
        int i = (blockIdx.y * 2 + blockIdx.x) * 256 + t;
        if (i < 36864) {
            // 32x32x16 B-frag order
            int j = i & 7, l = (i >> 3) & 63, ot = (i >> 9) & 1, s = i >> 10;
            int K = s * 16 + (l >> 5) * 8 + j;
            int o = ot * 32 + (l & 31);
            int c = K & 63, k = K >> 6;
            wdtf[i] = f2h(wd[(o * 64 + c) * 9 + k]);
        } else if (i < 36864 + 18432) {
            int jdx = i - 36864;
            int j = jdx & 7, l = (jdx >> 3) & 63, nt = (jdx >> 9) & 1, kcb = jdx >> 10;
            int k = kcb >> 1, cb = kcb & 1;
            int oc = nt * 16 + (l & 15);
            int c = cb * 32 + ((l >> 4) & 3) * 8 + j;
            wotf[jdx] = f2h(oc < 18 ? wo[(oc * 64 + c) * 9 + k] : 0.0f);
        }
        return;
    }
    __shared__ float tile[64 * 65];
    int w0 = blockIdx.x * 64, h = blockIdx.y, b = blockIdx.z;
    const float* xb = x + ((long)b * CC * HWSZ) + h * WW + w0;
#pragma unroll
    for (int i = 0; i < 16; ++i) {
        int idx = i * 256 + t; int c = idx >> 6, w = idx & 63;
        tile[c * 65 + w] = xb[c * HWSZ + w];
    }
    __syncthreads();
    unsigned short* xo = xh + ((long)((b * HH + h) * WW + w0)) * CC;
#pragma unroll
    for (int i = 0; i < 8; ++i) {
        int idx = i * 256 + t; int w = idx >> 5, c = (idx & 31) * 2;
        ushort2 u;
        u.x = f2h(tile[c * 65 + w]);
        u.y = f2h(tile[(c + 1) * 65 + w]);
        *(ushort2*)(xo + w * CC + c) = u;
    }
}

// ---------------------------------------------------------------------------
// K1: fused offset-conv + deform-conv. Block = (b,h,64px).
// Phase A: stage rows h-1..h+1 -> LDS (xr), 9x 16x16x32 MFMA -> offs LDS.
// Phase B: sample all 9 k (4 thr/px x 16ch, packed-fp16 bilinear) ->
//   val_s[64][584] -> barrier -> 32x32x16 GEMM, wave = 32px x 32o:
//   36 B-frags in VGPRs (loaded post-barrier), 36 ds_read_b128 A-frags,
//   36 MFMA — A-LDS traffic halved vs 16x16 path.
// ---------------------------------------------------------------------------
__global__ __launch_bounds__(256, 2) void fused_dcn(const unsigned short* __restrict__ xh,
                                                    const unsigned short* __restrict__ wotf,
                                                    const float* __restrict__ b_off,
                                                    const unsigned short* __restrict__ wdtf,
                                                    const float* __restrict__ b_dcn,
                                                    float* __restrict__ out) {
    __shared__ __attribute__((aligned(16))) unsigned short shm[64 * 584]; // union
    __shared__ float offs[64 * 20];
    unsigned short* xr    = shm;   // phase A: [row(3)][px(66,pad68)][ch(64,pad72)]
    unsigned short* val_s = shm;   // phase B: [px(64)][K(576,pad584)]

    int w0 = blockIdx.x * 64, h = blockIdx.y, b = blockIdx.z;
    int t = threadIdx.x;
    int l = t & 63, wv = t >> 6;
    int m = l & 15, q = l >> 4;

    // ================= phase A: offset conv (16x16x32) =================
#pragma unroll
    for (int i = 0; i < 7; ++i) {
        int idx = i * 256 + t;
        if (idx < 1584) {
            int r = idx / 528;
            int rem = idx - r * 528;
            int p = rem >> 3, cc = rem & 7;
            int y = h + r - 1, wx = w0 - 1 + p;
            uint4 v = make_uint4(0u, 0u, 0u, 0u);
            if (((unsigned)y < HH) && ((unsigned)wx < WW))
                v = *(const uint4*)(xh + ((long)((b * HH + y) * WW + wx)) * CC + cc * 8);
            *(uint4*)&xr[(r * 68 + p) * 72 + cc * 8] = v;
        }
    }
    __syncthreads();
    {
        int px0 = wv * 16;
        f32x4 acc0 = {0.f, 0.f, 0.f, 0.f}, acc1 = {0.f, 0.f, 0.f, 0.f};
#pragma unroll
        for (int k = 0; k < 9; ++k) {
            int ky = k / 3, kx = k - ky * 3;
            const unsigned short* ar = &xr[(ky * 68 + px0 + m + kx) * 72 + q * 8];
            f16x8 a0 = *(const f16x8*)(ar);
            f16x8 a1 = *(const f16x8*)(ar + 32);
            const unsigned short* bk = wotf + (k * 2) * 2 * 512 + l * 8;
            f16x8 b00 = *(const f16x8*)(bk);
            f16x8 b01 = *(const f16x8*)(bk + 512);
            f16x8 b10 = *(const f16x8*)(bk + 1024);
            f16x8 b11 = *(const f16x8*)(bk + 1536);
            acc0 = __builtin_amdgcn_mfma_f32_16x16x32_f16(a0, b00, acc0, 0, 0, 0);
            acc0 = __builtin_amdgcn_mfma_f32_16x16x32_f16(a1, b10, acc0, 0, 0, 0);
            acc1 = __builtin_amdgcn_mfma_f32_16x16x32_f16(a0, b01, acc1, 0, 0, 0);
            acc1 = __builtin_amdgcn_mfma_f32_16x16x32_f16(a1, b11, acc1, 0, 0, 0);
        }
        float bo0 = b_off[m];
#pragma unroll
        for (int r = 0; r < 4; ++r)
            offs[(px0 + q * 4 + r) * 20 + m] = acc0[r] + bo0;
        if (m < 2) {
            float bo1 = b_off[16 + m];
#pragma unroll
            for (int r = 0; r < 4; ++r)
                offs[(px0 + q * 4 + r) * 20 + 16 + m] = acc1[r] + bo1;
        }
    }
    __syncthreads();   // offs ready; xr dead

    // ================= phase B: sampling =================
    int spx = t >> 2, ch16 = (t & 3) * 16;   // sampler: pixel 0..63, 32B chunk

    const unsigned short* xb = xh + (long)b * HWSZ * CC;
    const float* oprow = &offs[spx * 20];

#pragma unroll
    for (int k = 0; k < 9; ++k) {
        int ky = k / 3, kx = k - ky * 3;
        float2 ov = *(const float2*)(oprow + 2 * k);
        float py  = (float)(h + ky - 1) + ov.x;
        float pxf = (float)(w0 + spx + kx - 1) + ov.y;
        float y0f = floorf(py), x0f = floorf(pxf);
        float wy = py - y0f, wx = pxf - x0f;
        int y0 = (int)y0f, x0 = (int)x0f, y1 = y0 + 1, x1 = x0 + 1;
        bool vy0 = (unsigned)y0 < HH, vy1 = (unsigned)y1 < HH;
        bool vx0 = (unsigned)x0 < WW, vx1 = (unsigned)x1 < WW;
        int y0c = min(max(y0, 0), HH - 1), y1c = min(max(y1, 0), HH - 1);
        int x0c = min(max(x0, 0), WW - 1), x1c = min(max(x1, 0), WW - 1);
        _Float16 h0 = (_Float16)((vy0 && vx0) ? (1.f - wy) * (1.f - wx) : 0.f);
        _Float16 h1 = (_Float16)((vy0 && vx1) ? (1.f - wy) * wx : 0.f);
        _Float16 h2 = (_Float16)((vy1 && vx0) ? wy * (1.f - wx) : 0.f);
        _Float16 h3 = (_Float16)((vy1 && vx1) ? wy * wx : 0.f);
        const unsigned short* p00 = xb + (y0c * WW + x0c) * CC + ch16;
        const unsigned short* p01 = xb + (y0c * WW + x1c) * CC + ch16;
        const unsigned short* p10 = xb + (y1c * WW + x0c) * CC + ch16;
        const unsigned short* p11 = xb + (y1c * WW + x1c) * CC + ch16;
        f16x8 s00a = *(const f16x8*)p00, s00b = *(const f16x8*)(p00 + 8);
        f16x8 s01a = *(const f16x8*)p01, s01b = *(const f16x8*)(p01 + 8);
        f16x8 s10a = *(const f16x8*)p10, s10b = *(const f16x8*)(p10 + 8);
        f16x8 s11a = *(const f16x8*)p11, s11b = *(const f16x8*)(p11 + 8);
        f16x8 alo = s00a * h0 + s01a * h1 + s10a * h2 + s11a * h3;  // v_pk_fma_f16
        f16x8 ahi = s00b * h0 + s01b * h1 + s10b * h2 + s11b * h3;
        *(f16x8*)&val_s[spx * 584 + k * 64 + ch16] = alo;
        *(f16x8*)&val_s[spx * 584 + k * 64 + ch16 + 8] = ahi;
    }
    __syncthreads();

    // ================= phase B: 32x32x16 GEMM, wave = 32px x 32o ==========
    int pxh = wv & 1;            // px-half: 0/1 -> px 0..31 / 32..63
    int oh  = wv >> 1;           // o-half:  0/1 -> o  0..31 / 32..63

    // B panel in registers: 36 frags, loaded after barrier (low pressure
    // during sampling). Each frag load = coalesced 1KB wave burst.
    f16x8 Breg[36];
#pragma unroll
    for (int s = 0; s < 36; ++s)
        Breg[s] = *(const f16x8*)(wdtf + ((s * 2 + oh) * 64 + l) * 8);

    f32x16 acc = {0.f};
    const unsigned short* arow = &val_s[(pxh * 32 + (l & 31)) * 584 + (l >> 5) * 8];
#pragma unroll
    for (int s = 0; s < 36; ++s) {
        f16x8 a = *(const f16x8*)(arow + s * 16);
        acc = __builtin_amdgcn_mfma_f32_32x32x16_f16(a, Breg[s], acc, 0, 0, 0);
    }

    // epilogue: col(o) = oh*32 + (l&31); row(px) = (reg&3)+8*(reg>>2)+4*(l>>5)
    int o = oh * 32 + (l & 31);
    float bo = b_dcn[o];
    float* outo = out + ((long)(b * OO + o)) * HWSZ + h * WW + w0 + pxh * 32 + 4 * (l >> 5);
#pragma unroll
    for (int rg = 0; rg < 4; ++rg) {
        f32x4 r;
        r[0] = acc[rg * 4 + 0] + bo;
        r[1] = acc[rg * 4 + 1] + bo;
        r[2] = acc[rg * 4 + 2] + bo;
        r[3] = acc[rg * 4 + 3] + bo;
        *(f32x4*)(outo + rg * 8) = r;
    }
}

// ---------------------------------------------------------------------------
extern "C" void kernel_launch(void* const* d_in, const int* in_sizes, int n_in,
                              void* d_out, int out_size, void* d_ws, size_t ws_size,
                              hipStream_t stream) {
    const float* x     = (const float*)d_in[0];
    const float* w_off = (const float*)d_in[1];
    const float* b_off = (const float*)d_in[2];
    const float* w_dcn = (const float*)d_in[3];
    const float* b_dcn = (const float*)d_in[4];
    float* out = (float*)d_out;

    char* ws = (char*)d_ws;
    unsigned short* xh   = (unsigned short*)ws;              //  8,388,608 B
    unsigned short* wdtf = (unsigned short*)(ws + 8388608);  //     73,728 B
    unsigned short* wotf = (unsigned short*)(ws + 8462336);  //     36,864 B

    hipLaunchKernelGGL(prep_all, dim3(2, 128, 5), dim3(256), 0, stream,
                       x, w_dcn, w_off, xh, wdtf, wotf);
    hipLaunchKernelGGL(fused_dcn, dim3(2, 128, 4), dim3(256), 0, stream,
                       xh, wotf, b_off, wdtf, b_dcn, out);
}

// Round 12
// 105.051 us; speedup vs baseline: 1.0157x; 1.0063x over previous
//
#include <hip/hip_runtime.h>
#include <hip/hip_fp16.h>

#define HH 128
#define WW 128
#define CC 64
#define OO 64
#define HWSZ (HH*WW)

typedef _Float16 f16x8 __attribute__((ext_vector_type(8)));
typedef float    f32x4 __attribute__((ext_vector_type(4)));

__device__ __forceinline__ unsigned short f2h(float f) {
    return __half_as_ushort(__float2half_rn(f));
}

// ---------------------------------------------------------------------------
// K0: prep_all. z<4: x NCHW fp32 -> NHWC fp16 (LDS-tiled transpose).
//     z==4: weight repack -> fp16 in MFMA B-fragment-major order (16x16x32):
//       wdtf[kc(18)][nt(4)][lane(64)][j(8)] : o=nt*16+(l&15), c=(kc&1)*32+((l>>4)&3)*8+j, k=kc>>1
//       wotf[kc(18)][nt(2)][lane(64)][j(8)] : same, oc>=18 zero-padded
// ---------------------------------------------------------------------------
__global__ __launch_bounds__(256) void prep_all(const float* __restrict__ x,
                                                const float* __restrict__ wd,
                                                const float* __restrict__ wo,
                                                unsigned short* __restrict__ xh,
                                                unsigned short* __restrict__ wdtf,
                                                unsigned short* __restrict__ wotf) {
    int t = threadIdx.x;
    if (blockIdx.z == 4) {
        int i = (blockIdx.y * 2 + blockIdx.x) * 256 + t;
        if (i < 36864) {
            int j = i & 7, l = (i >> 3) & 63, nt = (i >> 9) & 3, kcb = i >> 11;
            int k = kcb >> 1, cb = kcb & 1;
            int o = nt * 16 + (l & 15);
            int c = cb * 32 + ((l >> 4) & 3) * 8 + j;
            wdtf[i] = f2h(wd[(o * 64 + c) * 9 + k]);
        } else if (i < 36864 + 18432) {
            int jdx = i - 36864;
            int j = jdx & 7, l = (jdx >> 3) & 63, nt = (jdx >> 9) & 1, kcb = jdx >> 10;
            int k = kcb >> 1, cb = kcb & 1;
            int oc = nt * 16 + (l & 15);
            int c = cb * 32 + ((l >> 4) & 3) * 8 + j;
            wotf[jdx] = f2h(oc < 18 ? wo[(oc * 64 + c) * 9 + k] : 0.0f);
        }
        return;
    }
    __shared__ float tile[64 * 65];
    int w0 = blockIdx.x * 64, h = blockIdx.y, b = blockIdx.z;
    const float* xb = x + ((long)b * CC * HWSZ) + h * WW + w0;
#pragma unroll
    for (int i = 0; i < 16; ++i) {
        int idx = i * 256 + t; int c = idx >> 6, w = idx & 63;
        tile[c * 65 + w] = xb[c * HWSZ + w];
    }
    __syncthreads();
    unsigned short* xo = xh + ((long)((b * HH + h) * WW + w0)) * CC;
#pragma unroll
    for (int i = 0; i < 8; ++i) {
        int idx = i * 256 + t; int w = idx >> 5, c = (idx & 31) * 2;
        ushort2 u;
        u.x = f2h(tile[c * 65 + w]);
        u.y = f2h(tile[(c + 1) * 65 + w]);
        *(ushort2*)(xo + w * CC + c) = u;
    }
}

// ---------------------------------------------------------------------------
// K1: fused offset+deform conv, TWO output rows per block. Block = (b, 2 rows,
// 64 px). Grid 512 (halved): amortizes halo staging (4 rows vs 2x3), B-panel
// register load (once per 2 rows), launch/epilogue overhead.
// Phase A: stage rows h0-1..h0+2 -> xr LDS; 2 passes of 9x 16x16x32 MFMA
//   -> offs[128][20] LDS.
// Phase B: Breg[18] (72 VGPR) once; 4 sub-tiles (row r, half g) of 32 px:
//   sample 9k (8 thr/px x 8ch, packed-fp16 bilinear) -> val_s -> barrier ->
//   18x(2 ds_read_b128 + 2 MFMA) -> store -> barrier.
// LDS: union(xr 39.2KB, val_s 37.4KB) + offs 10.2KB = 49.4KB -> 3 blocks/CU.
// ---------------------------------------------------------------------------
__global__ __launch_bounds__(256, 3) void fused_dcn(const unsigned short* __restrict__ xh,
                                                    const unsigned short* __restrict__ wotf,
                                                    const float* __restrict__ b_off,
                                                    const unsigned short* __restrict__ wdtf,
                                                    const float* __restrict__ b_dcn,
                                                    float* __restrict__ out) {
    __shared__ __attribute__((aligned(16))) unsigned short shm[4 * 68 * 72]; // union
    __shared__ float offs[128 * 20];
    unsigned short* xr    = shm;   // phase A: [row(4)][px(66,pad68)][ch(64,pad72)]
    unsigned short* val_s = shm;   // phase B: [px(32)][K(576,pad584)]

    int w0 = blockIdx.x * 64, h0 = blockIdx.y * 2, b = blockIdx.z;
    int t = threadIdx.x;
    int l = t & 63, wv = t >> 6;
    int m = l & 15, q = l >> 4;

    // ================= phase A: stage 4 halo rows =================
#pragma unroll
    for (int i = 0; i < 9; ++i) {
        int idx = i * 256 + t;
        if (idx < 2112) {
            int r4 = idx / 528;
            int rem = idx - r4 * 528;
            int p = rem >> 3, cc = rem & 7;
            int y = h0 + r4 - 1, wx = w0 - 1 + p;
            uint4 v = make_uint4(0u, 0u, 0u, 0u);
            if (((unsigned)y < HH) && ((unsigned)wx < WW))
                v = *(const uint4*)(xh + ((long)((b * HH + y) * WW + wx)) * CC + cc * 8);
            *(uint4*)&xr[(r4 * 68 + p) * 72 + cc * 8] = v;
        }
    }
    __syncthreads();

    // ================= phase A: offset conv, 2 row passes =================
    {
        int px0 = wv * 16;
        float bo0 = b_off[m];
        float bo1 = (m < 2) ? b_off[16 + m] : 0.0f;
#pragma unroll
        for (int r = 0; r < 2; ++r) {
            f32x4 acc0 = {0.f, 0.f, 0.f, 0.f}, acc1 = {0.f, 0.f, 0.f, 0.f};
#pragma unroll
            for (int k = 0; k < 9; ++k) {
                int ky = k / 3, kx = k - ky * 3;
                const unsigned short* ar = &xr[((r + ky) * 68 + px0 + m + kx) * 72 + q * 8];
                f16x8 a0 = *(const f16x8*)(ar);
                f16x8 a1 = *(const f16x8*)(ar + 32);
                const unsigned short* bk = wotf + (k * 2) * 2 * 512 + l * 8;
                f16x8 b00 = *(const f16x8*)(bk);
                f16x8 b01 = *(const f16x8*)(bk + 512);
                f16x8 b10 = *(const f16x8*)(bk + 1024);
                f16x8 b11 = *(const f16x8*)(bk + 1536);
                acc0 = __builtin_amdgcn_mfma_f32_16x16x32_f16(a0, b00, acc0, 0, 0, 0);
                acc0 = __builtin_amdgcn_mfma_f32_16x16x32_f16(a1, b10, acc0, 0, 0, 0);
                acc1 = __builtin_amdgcn_mfma_f32_16x16x32_f16(a0, b01, acc1, 0, 0, 0);
                acc1 = __builtin_amdgcn_mfma_f32_16x16x32_f16(a1, b11, acc1, 0, 0, 0);
            }
#pragma unroll
            for (int rw = 0; rw < 4; ++rw)
                offs[(r * 64 + px0 + q * 4 + rw) * 20 + m] = acc0[rw] + bo0;
            if (m < 2) {
#pragma unroll
                for (int rw = 0; rw < 4; ++rw)
                    offs[(r * 64 + px0 + q * 4 + rw) * 20 + 16 + m] = acc1[rw] + bo1;
            }
        }
    }
    __syncthreads();   // offs ready; xr dead; val_s may now overwrite shm

    // ================= phase B: B panel once, 4 sub-tiles =================
    f16x8 Breg[18];
#pragma unroll
    for (int kc = 0; kc < 18; ++kc)
        Breg[kc] = *(const f16x8*)(wdtf + (kc * 4 + wv) * 512 + l * 8);

    const unsigned short* xb = xh + (long)b * HWSZ * CC;
    int spx = t >> 3, ch8 = (t & 7) * 8;    // sampler: pixel 0..31, 16B chunk
    int o = wv * 16 + m;
    float bo = b_dcn[o];

#pragma unroll
    for (int st = 0; st < 4; ++st) {
        int r = st >> 1, g = st & 1;
        int hrow = h0 + r;
        int wg0 = w0 + g * 32;
        const float* oprow = &offs[(r * 64 + g * 32 + spx) * 20];

        // ---- sampling: 9 k, independent gathers ----
#pragma unroll
        for (int k = 0; k < 9; ++k) {
            int ky = k / 3, kx = k - ky * 3;
            float2 ov = *(const float2*)(oprow + 2 * k);
            float py  = (float)(hrow + ky - 1) + ov.x;
            float pxf = (float)(wg0 + spx + kx - 1) + ov.y;
            float y0f = floorf(py), x0f = floorf(pxf);
            float wy = py - y0f, wx = pxf - x0f;
            int y0 = (int)y0f, x0 = (int)x0f, y1 = y0 + 1, x1 = x0 + 1;
            bool vy0 = (unsigned)y0 < HH, vy1 = (unsigned)y1 < HH;
            bool vx0 = (unsigned)x0 < WW, vx1 = (unsigned)x1 < WW;
            int y0c = min(max(y0, 0), HH - 1), y1c = min(max(y1, 0), HH - 1);
            int x0c = min(max(x0, 0), WW - 1), x1c = min(max(x1, 0), WW - 1);
            _Float16 h0w = (_Float16)((vy0 && vx0) ? (1.f - wy) * (1.f - wx) : 0.f);
            _Float16 h1w = (_Float16)((vy0 && vx1) ? (1.f - wy) * wx : 0.f);
            _Float16 h2w = (_Float16)((vy1 && vx0) ? wy * (1.f - wx) : 0.f);
            _Float16 h3w = (_Float16)((vy1 && vx1) ? wy * wx : 0.f);
            f16x8 s00 = *(const f16x8*)(xb + (y0c * WW + x0c) * CC + ch8);
            f16x8 s01 = *(const f16x8*)(xb + (y0c * WW + x1c) * CC + ch8);
            f16x8 s10 = *(const f16x8*)(xb + (y1c * WW + x0c) * CC + ch8);
            f16x8 s11 = *(const f16x8*)(xb + (y1c * WW + x1c) * CC + ch8);
            f16x8 a = s00 * h0w + s01 * h1w + s10 * h2w + s11 * h3w;  // v_pk_fma_f16
            *(f16x8*)&val_s[spx * 584 + k * 64 + ch8] = a;
        }
        __syncthreads();

        // ---- GEMM: K=576, B in regs ----
        f32x4 acc0 = {0.f, 0.f, 0.f, 0.f}, acc1 = {0.f, 0.f, 0.f, 0.f};
#pragma unroll
        for (int kc = 0; kc < 18; ++kc) {
            f16x8 a0 = *(const f16x8*)&val_s[m * 584 + kc * 32 + q * 8];
            f16x8 a1 = *(const f16x8*)&val_s[(16 + m) * 584 + kc * 32 + q * 8];
            acc0 = __builtin_amdgcn_mfma_f32_16x16x32_f16(a0, Breg[kc], acc0, 0, 0, 0);
            acc1 = __builtin_amdgcn_mfma_f32_16x16x32_f16(a1, Breg[kc], acc1, 0, 0, 0);
        }

        // ---- epilogue: px = q*4+rw (acc0) / 16+q*4+rw (acc1), col o ----
        float* outo = out + ((long)(b * OO + o) * HH + hrow) * WW + wg0;
        f32x4 r0 = acc0, r1 = acc1;
        r0[0] += bo; r0[1] += bo; r0[2] += bo; r0[3] += bo;
        r1[0] += bo; r1[1] += bo; r1[2] += bo; r1[3] += bo;
        *(f32x4*)(outo + q * 4) = r0;
        *(f32x4*)(outo + 16 + q * 4) = r1;
        if (st < 3) __syncthreads();   // val_s reuse fence
    }
}

// ---------------------------------------------------------------------------
extern "C" void kernel_launch(void* const* d_in, const int* in_sizes, int n_in,
                              void* d_out, int out_size, void* d_ws, size_t ws_size,
                              hipStream_t stream) {
    const float* x     = (const float*)d_in[0];
    const float* w_off = (const float*)d_in[1];
    const float* b_off = (const float*)d_in[2];
    const float* w_dcn = (const float*)d_in[3];
    const float* b_dcn = (const float*)d_in[4];
    float* out = (float*)d_out;

    char* ws = (char*)d_ws;
    unsigned short* xh   = (unsigned short*)ws;              //  8,388,608 B
    unsigned short* wdtf = (unsigned short*)(ws + 8388608);  //     73,728 B
    unsigned short* wotf = (unsigned short*)(ws + 8462336);  //     36,864 B

    hipLaunchKernelGGL(prep_all, dim3(2, 128, 5), dim3(256), 0, stream,
                       x, w_dcn, w_off, xh, wdtf, wotf);
    hipLaunchKernelGGL(fused_dcn, dim3(2, 64, 4), dim3(256), 0, stream,
                       xh, wotf, b_off, wdtf, b_dcn, out);
}

// Round 13
// 103.518 us; speedup vs baseline: 1.0307x; 1.0148x over previous
//
#include <hip/hip_runtime.h>
#include <hip/hip_fp16.h>

#define HH 128
#define WW 128
#define CC 64
#define OO 64
#define HWSZ (HH*WW)

typedef _Float16 f16x8 __attribute__((ext_vector_type(8)));
typedef float    f32x4 __attribute__((ext_vector_type(4)));

__device__ __forceinline__ unsigned short f2h(float f) {
    return __half_as_ushort(__float2half_rn(f));
}

// ---------------------------------------------------------------------------
// K0: prep_all. z<4: x NCHW fp32 -> NHWC fp16 (LDS-tiled transpose).
//     z==4: weight repack -> fp16 in MFMA B-fragment-major order (16x16x32):
//       wdtf[kc(18)][nt(4)][lane(64)][j(8)] : o=nt*16+(l&15), c=(kc&1)*32+((l>>4)&3)*8+j, k=kc>>1
//       wotf[kc(18)][nt(2)][lane(64)][j(8)] : same, oc>=18 zero-padded
// ---------------------------------------------------------------------------
__global__ __launch_bounds__(256) void prep_all(const float* __restrict__ x,
                                                const float* __restrict__ wd,
                                                const float* __restrict__ wo,
                                                unsigned short* __restrict__ xh,
                                                unsigned short* __restrict__ wdtf,
                                                unsigned short* __restrict__ wotf) {
    int t = threadIdx.x;
    if (blockIdx.z == 4) {
        int i = (blockIdx.y * 2 + blockIdx.x) * 256 + t;
        if (i < 36864) {
            int j = i & 7, l = (i >> 3) & 63, nt = (i >> 9) & 3, kcb = i >> 11;
            int k = kcb >> 1, cb = kcb & 1;
            int o = nt * 16 + (l & 15);
            int c = cb * 32 + ((l >> 4) & 3) * 8 + j;
            wdtf[i] = f2h(wd[(o * 64 + c) * 9 + k]);
        } else if (i < 36864 + 18432) {
            int jdx = i - 36864;
            int j = jdx & 7, l = (jdx >> 3) & 63, nt = (jdx >> 9) & 1, kcb = jdx >> 10;
            int k = kcb >> 1, cb = kcb & 1;
            int oc = nt * 16 + (l & 15);
            int c = cb * 32 + ((l >> 4) & 3) * 8 + j;
            wotf[jdx] = f2h(oc < 18 ? wo[(oc * 64 + c) * 9 + k] : 0.0f);
        }
        return;
    }
    __shared__ float tile[64 * 65];
    int w0 = blockIdx.x * 64, h = blockIdx.y, b = blockIdx.z;
    const float* xb = x + ((long)b * CC * HWSZ) + h * WW + w0;
#pragma unroll
    for (int i = 0; i < 16; ++i) {
        int idx = i * 256 + t; int c = idx >> 6, w = idx & 63;
        tile[c * 65 + w] = xb[c * HWSZ + w];
    }
    __syncthreads();
    unsigned short* xo = xh + ((long)((b * HH + h) * WW + w0)) * CC;
#pragma unroll
    for (int i = 0; i < 8; ++i) {
        int idx = i * 256 + t; int w = idx >> 5, c = (idx & 31) * 2;
        ushort2 u;
        u.x = f2h(tile[c * 65 + w]);
        u.y = f2h(tile[(c + 1) * 65 + w]);
        *(ushort2*)(xo + w * CC + c) = u;
    }
}

// ---------------------------------------------------------------------------
// K1: fused offset+deform conv (R9 structure + XCD-locality swizzle).
// Grid = 1024 linear. Decode pins all 32 blocks of one (b, 16-row band)
// group to one id%8 class (= one XCD): working set 288 KB/group, 1.2 MB/XCD
// -> sampling gathers hit that XCD's L2 instead of thrashing to HBM.
//   id = (g&7) + 8*((g>>3)*32 + inner),  g = b*8 + (h>>4),
//   inner = (h&15)*2 + xhalf.
// Phase A: stage rows h-1..h+1 -> xr, 9x 16x16x32 MFMA -> offs LDS.
// Phase B: Breg[18] in VGPRs; 2 sub-tiles of 32 px: sample 9k (8 thr/px x
//   8ch, packed-fp16 bilinear) -> val_s -> barrier -> 18x(2 ds_read + 2 MFMA).
// LDS: union(xr 29.4KB, val_s 37.4KB) + offs 5.1KB = 42.5KB -> 3 blocks/CU.
// ---------------------------------------------------------------------------
__global__ __launch_bounds__(256, 3) void fused_dcn(const unsigned short* __restrict__ xh,
                                                    const unsigned short* __restrict__ wotf,
                                                    const float* __restrict__ b_off,
                                                    const unsigned short* __restrict__ wdtf,
                                                    const float* __restrict__ b_dcn,
                                                    float* __restrict__ out) {
    __shared__ __attribute__((aligned(16))) unsigned short shm[32 * 584]; // union
    __shared__ float offs[64 * 20];
    unsigned short* xr    = shm;   // phase A: [row(3)][px(66,pad68)][ch(64,pad72)]
    unsigned short* val_s = shm;   // phase B: [px(32)][K(576,pad584)]

    // ---- XCD-locality decode ----
    int id = blockIdx.x;
    int c8 = id & 7;           // XCD class
    int j  = id >> 3;
    int g  = (j >> 5) * 8 + c8;        // group 0..31 = b*8 + (h>>4)
    int inner = j & 31;
    int b  = g >> 3;
    int h  = (g & 7) * 16 + (inner >> 1);
    int w0 = (inner & 1) * 64;

    int t = threadIdx.x;
    int l = t & 63, wv = t >> 6;
    int m = l & 15, q = l >> 4;

    // ================= phase A: offset conv =================
#pragma unroll
    for (int i = 0; i < 7; ++i) {
        int idx = i * 256 + t;
        if (idx < 1584) {
            int r = idx / 528;
            int rem = idx - r * 528;
            int p = rem >> 3, cc = rem & 7;
            int y = h + r - 1, wx = w0 - 1 + p;
            uint4 v = make_uint4(0u, 0u, 0u, 0u);
            if (((unsigned)y < HH) && ((unsigned)wx < WW))
                v = *(const uint4*)(xh + ((long)((b * HH + y) * WW + wx)) * CC + cc * 8);
            *(uint4*)&xr[(r * 68 + p) * 72 + cc * 8] = v;
        }
    }
    __syncthreads();
    {
        int px0 = wv * 16;
        f32x4 acc0 = {0.f, 0.f, 0.f, 0.f}, acc1 = {0.f, 0.f, 0.f, 0.f};
#pragma unroll
        for (int k = 0; k < 9; ++k) {
            int ky = k / 3, kx = k - ky * 3;
            const unsigned short* ar = &xr[(ky * 68 + px0 + m + kx) * 72 + q * 8];
            f16x8 a0 = *(const f16x8*)(ar);
            f16x8 a1 = *(const f16x8*)(ar + 32);
            const unsigned short* bk = wotf + (k * 2) * 2 * 512 + l * 8;
            f16x8 b00 = *(const f16x8*)(bk);
            f16x8 b01 = *(const f16x8*)(bk + 512);
            f16x8 b10 = *(const f16x8*)(bk + 1024);
            f16x8 b11 = *(const f16x8*)(bk + 1536);
            acc0 = __builtin_amdgcn_mfma_f32_16x16x32_f16(a0, b00, acc0, 0, 0, 0);
            acc0 = __builtin_amdgcn_mfma_f32_16x16x32_f16(a1, b10, acc0, 0, 0, 0);
            acc1 = __builtin_amdgcn_mfma_f32_16x16x32_f16(a0, b01, acc1, 0, 0, 0);
            acc1 = __builtin_amdgcn_mfma_f32_16x16x32_f16(a1, b11, acc1, 0, 0, 0);
        }
        float bo0 = b_off[m];
#pragma unroll
        for (int r = 0; r < 4; ++r)
            offs[(px0 + q * 4 + r) * 20 + m] = acc0[r] + bo0;
        if (m < 2) {
            float bo1 = b_off[16 + m];
#pragma unroll
            for (int r = 0; r < 4; ++r)
                offs[(px0 + q * 4 + r) * 20 + 16 + m] = acc1[r] + bo1;
        }
    }
    __syncthreads();   // offs ready; xr dead; val_s may now overwrite shm

    // ================= phase B: deform conv =================
    int spx = t >> 3, ch8 = (t & 7) * 8;    // sampler: pixel 0..31, 16B chunk

    f16x8 Breg[18];
#pragma unroll
    for (int kc = 0; kc < 18; ++kc)
        Breg[kc] = *(const f16x8*)(wdtf + (kc * 4 + wv) * 512 + l * 8);

    const unsigned short* xb = xh + (long)b * HWSZ * CC;
    int o = wv * 16 + m;
    float bo = b_dcn[o];
    float* outo = out + ((long)(b * OO + o)) * HWSZ + h * WW;

#pragma unroll
    for (int g2 = 0; g2 < 2; ++g2) {
        int wg0 = w0 + g2 * 32;
        const float* oprow = &offs[(g2 * 32 + spx) * 20];

#pragma unroll
        for (int k = 0; k < 9; ++k) {
            int ky = k / 3, kx = k - ky * 3;
            float2 ov = *(const float2*)(oprow + 2 * k);
            float py  = (float)(h + ky - 1) + ov.x;
            float pxf = (float)(wg0 + spx + kx - 1) + ov.y;
            float y0f = floorf(py), x0f = floorf(pxf);
            float wy = py - y0f, wx = pxf - x0f;
            int y0 = (int)y0f, x0 = (int)x0f, y1 = y0 + 1, x1 = x0 + 1;
            bool vy0 = (unsigned)y0 < HH, vy1 = (unsigned)y1 < HH;
            bool vx0 = (unsigned)x0 < WW, vx1 = (unsigned)x1 < WW;
            int y0c = min(max(y0, 0), HH - 1), y1c = min(max(y1, 0), HH - 1);
            int x0c = min(max(x0, 0), WW - 1), x1c = min(max(x1, 0), WW - 1);
            _Float16 h0w = (_Float16)((vy0 && vx0) ? (1.f - wy) * (1.f - wx) : 0.f);
            _Float16 h1w = (_Float16)((vy0 && vx1) ? (1.f - wy) * wx : 0.f);
            _Float16 h2w = (_Float16)((vy1 && vx0) ? wy * (1.f - wx) : 0.f);
            _Float16 h3w = (_Float16)((vy1 && vx1) ? wy * wx : 0.f);
            f16x8 s00 = *(const f16x8*)(xb + (y0c * WW + x0c) * CC + ch8);
            f16x8 s01 = *(const f16x8*)(xb + (y0c * WW + x1c) * CC + ch8);
            f16x8 s10 = *(const f16x8*)(xb + (y1c * WW + x0c) * CC + ch8);
            f16x8 s11 = *(const f16x8*)(xb + (y1c * WW + x1c) * CC + ch8);
            f16x8 a = s00 * h0w + s01 * h1w + s10 * h2w + s11 * h3w;  // v_pk_fma_f16
            *(f16x8*)&val_s[spx * 584 + k * 64 + ch8] = a;
        }
        __syncthreads();

        f32x4 acc0 = {0.f, 0.f, 0.f, 0.f}, acc1 = {0.f, 0.f, 0.f, 0.f};
#pragma unroll
        for (int kc = 0; kc < 18; ++kc) {
            f16x8 a0 = *(const f16x8*)&val_s[m * 584 + kc * 32 + q * 8];
            f16x8 a1 = *(const f16x8*)&val_s[(16 + m) * 584 + kc * 32 + q * 8];
            acc0 = __builtin_amdgcn_mfma_f32_16x16x32_f16(a0, Breg[kc], acc0, 0, 0, 0);
            acc1 = __builtin_amdgcn_mfma_f32_16x16x32_f16(a1, Breg[kc], acc1, 0, 0, 0);
        }

        f32x4 r0 = acc0, r1 = acc1;
        r0[0] += bo; r0[1] += bo; r0[2] += bo; r0[3] += bo;
        r1[0] += bo; r1[1] += bo; r1[2] += bo; r1[3] += bo;
        *(f32x4*)(outo + wg0 + q * 4) = r0;
        *(f32x4*)(outo + wg0 + 16 + q * 4) = r1;
        if (g2 == 0) __syncthreads();   // val_s reuse fence
    }
}

// ---------------------------------------------------------------------------
extern "C" void kernel_launch(void* const* d_in, const int* in_sizes, int n_in,
                              void* d_out, int out_size, void* d_ws, size_t ws_size,
                              hipStream_t stream) {
    const float* x     = (const float*)d_in[0];
    const float* w_off = (const float*)d_in[1];
    const float* b_off = (const float*)d_in[2];
    const float* w_dcn = (const float*)d_in[3];
    const float* b_dcn = (const float*)d_in[4];
    float* out = (float*)d_out;

    char* ws = (char*)d_ws;
    unsigned short* xh   = (unsigned short*)ws;              //  8,388,608 B
    unsigned short* wdtf = (unsigned short*)(ws + 8388608);  //     73,728 B
    unsigned short* wotf = (unsigned short*)(ws + 8462336);  //     36,864 B

    hipLaunchKernelGGL(prep_all, dim3(2, 128, 5), dim3(256), 0, stream,
                       x, w_dcn, w_off, xh, wdtf, wotf);
    hipLaunchKernelGGL(fused_dcn, dim3(1024), dim3(256), 0, stream,
                       xh, wotf, b_off, wdtf, b_dcn, out);
}